// Round 1
// baseline (3275.579 us; speedup 1.0000x reference)
//
#include <hip/hip_runtime.h>
#include <hip/hip_bf16.h>

typedef __bf16 bf16;
typedef __bf16 bf16x8 __attribute__((ext_vector_type(8)));
typedef float f32x4 __attribute__((ext_vector_type(4)));

#define S_ 512
#define N_ 64
#define C_ 512
#define V_ 10
#define Q_ 256
#define NWG_LSTM 64

// ---- workspace layout (bytes) ----
#define OFF_A0   ((size_t)0)
#define OFF_A1   (OFF_A0 + (size_t)S_ * N_ * 4)
#define OFF_PW   (OFF_A1 + (size_t)S_ * N_ * 4)            // bf16 [N][Q][S]
#define OFF_QU   (OFF_PW + (size_t)N_ * Q_ * S_ * 2)       // bf16 [Q][N][C] row=(q*N+n)
#define OFF_H    (OFF_QU + (size_t)Q_ * N_ * C_ * 2)       // bf16 [2][N][C]
#define OFF_HS   (OFF_H + (size_t)2 * N_ * C_ * 2)         // bf16 [Q][N][C]
#define OFF_BAR  (OFF_HS + (size_t)Q_ * N_ * C_ * 2)

__device__ __forceinline__ float sigf(float x) { return 1.f / (1.f + __expf(-x)); }
__device__ __forceinline__ float tanhf_(float x) { return 1.f - 2.f / (__expf(2.f * x) + 1.f); }

// ---------------- stage 1: action softmax ----------------
// wave per (s,n) row; A0/A1 stored [n][s] for posvec-friendly reads.
__global__ __launch_bounds__(256) void k_actions(const float* __restrict__ mem,
    const float* __restrict__ Wact, const float* __restrict__ bact,
    float* __restrict__ A0, float* __restrict__ A1) {
  const int wid = threadIdx.x >> 6, lane = threadIdx.x & 63;
  const int row = blockIdx.x * 4 + wid;          // row = s*64 + n
  const int s = row >> 6, n = row & 63;
  const float* mrow = mem + (size_t)row * C_ + lane * 8;
  const float* wrow = Wact + (size_t)lane * 16;  // W_act[c][2], c = lane*8..
  float4 m0 = *(const float4*)(mrow);
  float4 m1 = *(const float4*)(mrow + 4);
  float d0 = 0.f, d1 = 0.f;
  float mv[8] = {m0.x, m0.y, m0.z, m0.w, m1.x, m1.y, m1.z, m1.w};
#pragma unroll
  for (int j = 0; j < 8; ++j) {
    d0 += mv[j] * wrow[j * 2 + 0];
    d1 += mv[j] * wrow[j * 2 + 1];
  }
#pragma unroll
  for (int m = 32; m >= 1; m >>= 1) {
    d0 += __shfl_xor(d0, m);
    d1 += __shfl_xor(d1, m);
  }
  if (lane == 0) {
    float l0 = d0 + bact[0], l1 = d1 + bact[1];
    float mx = fmaxf(l0, l1);
    float e0 = __expf(l0 - mx), e1 = __expf(l1 - mx);
    float inv = 1.f / (e0 + e1);
    A0[(size_t)n * S_ + s] = e0 * inv;
    A1[(size_t)n * S_ + s] = e1 * inv;
  }
}

// ---------------- stage 2: posvec scan ----------------
// 1 WG per n; thread t owns q=t. Emits Pw[n][q][s] = posvec_pre[s][q]*a1[s] (bf16).
__global__ __launch_bounds__(256) void k_posvec(const float* __restrict__ A0,
    const float* __restrict__ A1, bf16* __restrict__ Pw) {
  __shared__ float a0s[S_], a1s[S_];
  __shared__ float pbuf[2][Q_];
  const int n = blockIdx.x, t = threadIdx.x;
  a0s[t] = A0[(size_t)n * S_ + t];
  a0s[t + 256] = A0[(size_t)n * S_ + t + 256];
  a1s[t] = A1[(size_t)n * S_ + t];
  a1s[t + 256] = A1[(size_t)n * S_ + t + 256];
  float p = (t == 0) ? 1.f : 0.f;
  __syncthreads();
  for (int s8 = 0; s8 < S_; s8 += 8) {
    float emit[8];
#pragma unroll
    for (int jj = 0; jj < 8; ++jj) {
      const int s = s8 + jj;
      pbuf[jj & 1][t] = p;
      __syncthreads();
      float pm1 = pbuf[jj & 1][(t + Q_ - 1) & (Q_ - 1)];
      float a0 = a0s[s], a1 = a1s[s];
      emit[jj] = p * a1;                 // emit BEFORE update
      p = fmaf(pm1, a1, p * a0);
    }
    bf16x8 v;
#pragma unroll
    for (int jj = 0; jj < 8; ++jj) v[jj] = (bf16)emit[jj];
    *(bf16x8*)(Pw + ((size_t)n * Q_ + t) * S_ + s8) = v;
  }
}

// ---------------- stage 3: queue einsum (per-n GEMM, bf16 MFMA) ----------------
// queue[q][n][c] = sum_s Pw[n][q][s] * mem[s][n][c]
__global__ __launch_bounds__(256) void k_queue(const bf16* __restrict__ Pw,
    const float* __restrict__ mem, bf16* __restrict__ qout) {
  __shared__ bf16 bt[64 * 32];  // B tile [c_loc][k], XOR-swizzled 16B blocks
  const int bid = blockIdx.x;
  const int n = bid >> 5, qt = (bid >> 3) & 3, ct = bid & 7;
  const int q0 = qt * 64, c0 = ct * 64;
  const int t = threadIdx.x, wid = t >> 6, lane = t & 63;
  const int lrow = lane & 15, lkb = lane >> 4;
  f32x4 acc[4] = {};
  const bf16* arow = Pw + ((size_t)n * Q_ + q0 + wid * 16 + lrow) * S_ + lkb * 8;
  const int sl = t >> 3, cb = (t & 7) * 8;
  const float* msrc = mem + ((size_t)sl * N_ + n) * C_ + c0 + cb;
  for (int kb = 0; kb < 16; ++kb) {
    float4 f0 = *(const float4*)(msrc + (size_t)kb * 32 * N_ * C_);
    float4 f1 = *(const float4*)(msrc + (size_t)kb * 32 * N_ * C_ + 4);
    __syncthreads();  // previous iteration's B reads complete
    float fv[8] = {f0.x, f0.y, f0.z, f0.w, f1.x, f1.y, f1.z, f1.w};
#pragma unroll
    for (int jw = 0; jw < 8; ++jw) {
      const int row = cb + jw;
      bt[row * 32 + ((((sl >> 3) ^ (row & 3)) << 3) | (sl & 7))] = (bf16)fv[jw];
    }
    __syncthreads();
    bf16x8 a = *(const bf16x8*)(arow + kb * 32);
#pragma unroll
    for (int cs = 0; cs < 4; ++cs) {
      const int row = cs * 16 + lrow;
      bf16x8 b = *(const bf16x8*)(&bt[row * 32 + ((lkb ^ (row & 3)) << 3)]);
      acc[cs] = __builtin_amdgcn_mfma_f32_16x16x32_bf16(a, b, acc[cs], 0, 0, 0);
    }
  }
#pragma unroll
  for (int cs = 0; cs < 4; ++cs) {
#pragma unroll
    for (int r = 0; r < 4; ++r) {
      const int q = q0 + wid * 16 + (lane >> 4) * 4 + r;
      const int c = c0 + cs * 16 + lrow;
      qout[((size_t)q * N_ + n) * C_ + c] = (bf16)acc[cs][r];
    }
  }
}

// ---------------- device-wide barrier (sense-reversal, agent scope) ----------------
__device__ __forceinline__ void gridbar(int* cnt, int* gen, int nwg) {
  __syncthreads();
  if (threadIdx.x == 0) {
    __threadfence();  // release: flush L2 (covers all waves' stores; vmcnt drained at barrier)
    int g = __hip_atomic_load(gen, __ATOMIC_ACQUIRE, __HIP_MEMORY_SCOPE_AGENT);
    int a = __hip_atomic_fetch_add(cnt, 1, __ATOMIC_ACQ_REL, __HIP_MEMORY_SCOPE_AGENT);
    if (a == nwg - 1) {
      __hip_atomic_store(cnt, 0, __ATOMIC_RELAXED, __HIP_MEMORY_SCOPE_AGENT);
      __hip_atomic_store(gen, g + 1, __ATOMIC_RELEASE, __HIP_MEMORY_SCOPE_AGENT);
    } else {
      while (__hip_atomic_load(gen, __ATOMIC_ACQUIRE, __HIP_MEMORY_SCOPE_AGENT) == g) {
        __builtin_amdgcn_s_sleep(2);
      }
    }
    __threadfence();  // acquire: invalidate stale L1/L2 for h reads
  }
  __syncthreads();
}

// ---------------- stage 4: LSTM (persistent, 64 WGs, 1 barrier/step) ----------------
// WG w owns output channels co = w*8..w*8+8 (gate cols interleaved: col j -> gate j&3, co_loc j>>2).
__global__ __launch_bounds__(256) void k_lstm(
    const bf16* __restrict__ queue, const float* __restrict__ Wih,
    const float* __restrict__ Whh, const float* __restrict__ bih,
    const float* __restrict__ bhh, bf16* __restrict__ H,
    bf16* __restrict__ hs, int* __restrict__ bar) {
  __shared__ bf16 Bx[32 * 512];
  __shared__ bf16 Bh[32 * 512];
  __shared__ float gbuf[4][16][33];
  __shared__ float bias[32];
  const int w = blockIdx.x, t = threadIdx.x;
  const int wid = t >> 6, lane = t & 63;

  {  // stage W_ih/W_hh slices into LDS (bf16, XOR-swizzled 16B blocks)
    const int j = t >> 3, k0 = (t & 7) * 64;
    const int r = 512 * (j & 3) + w * 8 + (j >> 2);
    const float* si = Wih + (size_t)r * C_ + k0;
    const float* sh = Whh + (size_t)r * C_ + k0;
#pragma unroll
    for (int u = 0; u < 64; u += 8) {
      float4 xa = *(const float4*)(si + u);
      float4 xb = *(const float4*)(si + u + 4);
      float4 ha = *(const float4*)(sh + u);
      float4 hb = *(const float4*)(sh + u + 4);
      const int k = k0 + u;
      const int idx = j * 512 + ((((k >> 3) ^ (j & 7)) << 3));
      bf16x8 vx, vh;
      vx[0] = (bf16)xa.x; vx[1] = (bf16)xa.y; vx[2] = (bf16)xa.z; vx[3] = (bf16)xa.w;
      vx[4] = (bf16)xb.x; vx[5] = (bf16)xb.y; vx[6] = (bf16)xb.z; vx[7] = (bf16)xb.w;
      vh[0] = (bf16)ha.x; vh[1] = (bf16)ha.y; vh[2] = (bf16)ha.z; vh[3] = (bf16)ha.w;
      vh[4] = (bf16)hb.x; vh[5] = (bf16)hb.y; vh[6] = (bf16)hb.z; vh[7] = (bf16)hb.w;
      *(bf16x8*)(&Bx[idx]) = vx;
      *(bf16x8*)(&Bh[idx]) = vh;
    }
    if (t < 32) {
      const int rr = 512 * (t & 3) + w * 8 + (t >> 2);
      bias[t] = bih[rr] + bhh[rr];
    }
    bf16* h0 = H + (size_t)w * C_;  // zero H[0] row n=w
    h0[t] = (bf16)0.f;
    h0[t + 256] = (bf16)0.f;
  }
  __syncthreads();
  gridbar(bar, bar + 1, NWG_LSTM);

  float cst0 = 0.f, cst1 = 0.f;
  const int arow = lane & 15, akc = (lane >> 4) * 8;
  const int j0 = lane & 15, j1 = 16 + (lane & 15);
  const int eco = lane & 7, en0 = lane >> 3, en1 = 8 + (lane >> 3);

  for (int step = 0; step < Q_; ++step) {
    const int cur = step & 1, nxt = cur ^ 1;
    const bf16* hbase = H + ((size_t)cur * N_ + wid * 16 + arow) * C_ + akc;
    const bf16* xbase = queue + ((size_t)step * N_ + wid * 16 + arow) * C_ + akc;
    f32x4 acc0 = {0.f, 0.f, 0.f, 0.f}, acc1 = {0.f, 0.f, 0.f, 0.f};
#pragma unroll
    for (int kb = 0; kb < 16; ++kb) {
      const int k = kb * 32 + akc;
      bf16x8 ah = *(const bf16x8*)(hbase + kb * 32);
      bf16x8 ax = *(const bf16x8*)(xbase + kb * 32);
      const int i0 = j0 * 512 + ((((k >> 3) ^ (j0 & 7)) << 3));
      const int i1 = j1 * 512 + ((((k >> 3) ^ (j1 & 7)) << 3));
      bf16x8 bx0 = *(const bf16x8*)(&Bx[i0]);
      bf16x8 bh0 = *(const bf16x8*)(&Bh[i0]);
      bf16x8 bx1 = *(const bf16x8*)(&Bx[i1]);
      bf16x8 bh1 = *(const bf16x8*)(&Bh[i1]);
      acc0 = __builtin_amdgcn_mfma_f32_16x16x32_bf16(ax, bx0, acc0, 0, 0, 0);
      acc0 = __builtin_amdgcn_mfma_f32_16x16x32_bf16(ah, bh0, acc0, 0, 0, 0);
      acc1 = __builtin_amdgcn_mfma_f32_16x16x32_bf16(ax, bx1, acc1, 0, 0, 0);
      acc1 = __builtin_amdgcn_mfma_f32_16x16x32_bf16(ah, bh1, acc1, 0, 0, 0);
    }
#pragma unroll
    for (int r = 0; r < 4; ++r) {
      gbuf[wid][(lane >> 4) * 4 + r][j0] = acc0[r];
      gbuf[wid][(lane >> 4) * 4 + r][16 + j0] = acc1[r];
    }
    __syncthreads();
    {  // elementwise: 2 (n_loc, co) items per lane; c-state in registers
      float gi = gbuf[wid][en0][eco * 4 + 0] + bias[eco * 4 + 0];
      float gf = gbuf[wid][en0][eco * 4 + 1] + bias[eco * 4 + 1];
      float gg = gbuf[wid][en0][eco * 4 + 2] + bias[eco * 4 + 2];
      float go = gbuf[wid][en0][eco * 4 + 3] + bias[eco * 4 + 3];
      cst0 = sigf(gf) * cst0 + sigf(gi) * tanhf_(gg);
      float hv = sigf(go) * tanhf_(cst0);
      bf16 hb = (bf16)hv;
      const int n = wid * 16 + en0, cg = w * 8 + eco;
      H[((size_t)nxt * N_ + n) * C_ + cg] = hb;
      hs[((size_t)step * N_ + n) * C_ + cg] = hb;
    }
    {
      float gi = gbuf[wid][en1][eco * 4 + 0] + bias[eco * 4 + 0];
      float gf = gbuf[wid][en1][eco * 4 + 1] + bias[eco * 4 + 1];
      float gg = gbuf[wid][en1][eco * 4 + 2] + bias[eco * 4 + 2];
      float go = gbuf[wid][en1][eco * 4 + 3] + bias[eco * 4 + 3];
      cst1 = sigf(gf) * cst1 + sigf(gi) * tanhf_(gg);
      float hv = sigf(go) * tanhf_(cst1);
      bf16 hb = (bf16)hv;
      const int n = wid * 16 + en1, cg = w * 8 + eco;
      H[((size_t)nxt * N_ + n) * C_ + cg] = hb;
      hs[((size_t)step * N_ + n) * C_ + cg] = hb;
    }
    gridbar(bar, bar + 1, NWG_LSTM);
  }
}

// ---------------- stage 5: LayerNorm + decode ----------------
__global__ __launch_bounds__(256) void k_lndec(const bf16* __restrict__ hs,
    const float* __restrict__ gamma, const float* __restrict__ beta,
    const float* __restrict__ Wdec, const float* __restrict__ bdec,
    float* __restrict__ out) {
  const int wid = threadIdx.x >> 6, lane = threadIdx.x & 63;
  const int row = blockIdx.x * 4 + wid;  // t*64 + n
  const bf16* hrow = hs + (size_t)row * C_ + lane * 8;
  bf16x8 hv = *(const bf16x8*)hrow;
  float h[8];
  float sm = 0.f, sq = 0.f;
#pragma unroll
  for (int j = 0; j < 8; ++j) {
    h[j] = (float)hv[j];
    sm += h[j];
    sq += h[j] * h[j];
  }
#pragma unroll
  for (int m = 32; m >= 1; m >>= 1) {
    sm += __shfl_xor(sm, m);
    sq += __shfl_xor(sq, m);
  }
  const float mu = sm * (1.f / C_);
  const float var = sq * (1.f / C_) - mu * mu;
  const float rs = 1.f / sqrtf(var + 1e-5f);
  float o[V_] = {};
#pragma unroll
  for (int j = 0; j < 8; ++j) {
    const int cj = lane * 8 + j;
    const float nv = (h[j] - mu) * rs * gamma[cj] + beta[cj];
    const float* wr = Wdec + (size_t)cj * V_;
#pragma unroll
    for (int v = 0; v < V_; ++v) o[v] += nv * wr[v];
  }
#pragma unroll
  for (int v = 0; v < V_; ++v) {
#pragma unroll
    for (int m = 32; m >= 1; m >>= 1) o[v] += __shfl_xor(o[v], m);
  }
  if (lane == 0) {
#pragma unroll
    for (int v = 0; v < V_; ++v) out[(size_t)row * V_ + v] = o[v] + bdec[v];
  }
}

extern "C" void kernel_launch(void* const* d_in, const int* in_sizes, int n_in,
                              void* d_out, int out_size, void* d_ws, size_t ws_size,
                              hipStream_t stream) {
  (void)in_sizes; (void)n_in; (void)out_size; (void)ws_size;
  const float* mem  = (const float*)d_in[0];
  const float* Wact = (const float*)d_in[1];
  const float* bact = (const float*)d_in[2];
  const float* Wih  = (const float*)d_in[3];
  const float* Whh  = (const float*)d_in[4];
  const float* bih  = (const float*)d_in[5];
  const float* bhh  = (const float*)d_in[6];
  const float* gam  = (const float*)d_in[7];
  const float* bet  = (const float*)d_in[8];
  const float* Wdec = (const float*)d_in[9];
  const float* bdec = (const float*)d_in[10];
  float* out = (float*)d_out;

  char* ws = (char*)d_ws;
  float* A0 = (float*)(ws + OFF_A0);
  float* A1 = (float*)(ws + OFF_A1);
  bf16* Pw  = (bf16*)(ws + OFF_PW);
  bf16* qu  = (bf16*)(ws + OFF_QU);
  bf16* H   = (bf16*)(ws + OFF_H);
  bf16* hs  = (bf16*)(ws + OFF_HS);
  int* bar  = (int*)(ws + OFF_BAR);

  hipMemsetAsync(bar, 0, 256, stream);
  k_actions<<<(S_ * N_) / 4, 256, 0, stream>>>(mem, Wact, bact, A0, A1);
  k_posvec<<<N_, 256, 0, stream>>>(A0, A1, Pw);
  k_queue<<<N_ * 32, 256, 0, stream>>>(Pw, mem, qu);
  k_lstm<<<NWG_LSTM, 256, 0, stream>>>(qu, Wih, Whh, bih, bhh, H, hs, bar);
  k_lndec<<<(Q_ * N_) / 4, 256, 0, stream>>>(hs, gam, bet, Wdec, bdec, out);
}

// Round 2
// 1771.288 us; speedup vs baseline: 1.8493x; 1.8493x over previous
//
#include <hip/hip_runtime.h>
#include <hip/hip_bf16.h>

typedef __bf16 bf16;
typedef __bf16 bf16x8 __attribute__((ext_vector_type(8)));
typedef float f32x4 __attribute__((ext_vector_type(4)));
typedef float f32x16 __attribute__((ext_vector_type(16)));

#define S_ 512
#define N_ 64
#define C_ 512
#define V_ 10
#define Q_ 256
#define NWG_LSTM 64

// ---- workspace layout (bytes) ----
#define OFF_A0   ((size_t)0)
#define OFF_A1   (OFF_A0 + (size_t)S_ * N_ * 4)
#define OFF_PW   (OFF_A1 + (size_t)S_ * N_ * 4)            // bf16 [N][Q][S]
#define OFF_QU   (OFF_PW + (size_t)N_ * Q_ * S_ * 2)       // bf16 [Q][N][C]
#define OFF_H    (OFF_QU + (size_t)Q_ * N_ * C_ * 2)       // bf16 [2][N][C]
#define OFF_HS   (OFF_H + (size_t)2 * N_ * C_ * 2)         // bf16 [Q][N][C]
#define OFF_BAR  (OFF_HS + (size_t)Q_ * N_ * C_ * 2)       // int flags[64]

__device__ __forceinline__ float sigf(float x) { return 1.f / (1.f + __expf(-x)); }
__device__ __forceinline__ float tanhf_(float x) { return 1.f - 2.f / (__expf(2.f * x) + 1.f); }

// ---------------- stage 1: action softmax ----------------
__global__ __launch_bounds__(256) void k_actions(const float* __restrict__ mem,
    const float* __restrict__ Wact, const float* __restrict__ bact,
    float* __restrict__ A0, float* __restrict__ A1) {
  const int wid = threadIdx.x >> 6, lane = threadIdx.x & 63;
  const int row = blockIdx.x * 4 + wid;          // row = s*64 + n
  const int s = row >> 6, n = row & 63;
  const float* mrow = mem + (size_t)row * C_ + lane * 8;
  const float* wrow = Wact + (size_t)lane * 16;
  float4 m0 = *(const float4*)(mrow);
  float4 m1 = *(const float4*)(mrow + 4);
  float d0 = 0.f, d1 = 0.f;
  float mv[8] = {m0.x, m0.y, m0.z, m0.w, m1.x, m1.y, m1.z, m1.w};
#pragma unroll
  for (int j = 0; j < 8; ++j) {
    d0 += mv[j] * wrow[j * 2 + 0];
    d1 += mv[j] * wrow[j * 2 + 1];
  }
#pragma unroll
  for (int m = 32; m >= 1; m >>= 1) {
    d0 += __shfl_xor(d0, m);
    d1 += __shfl_xor(d1, m);
  }
  if (lane == 0) {
    float l0 = d0 + bact[0], l1 = d1 + bact[1];
    float mx = fmaxf(l0, l1);
    float e0 = __expf(l0 - mx), e1 = __expf(l1 - mx);
    float inv = 1.f / (e0 + e1);
    A0[(size_t)n * S_ + s] = e0 * inv;
    A1[(size_t)n * S_ + s] = e1 * inv;
  }
}

// ---------------- stage 2: posvec scan ----------------
__global__ __launch_bounds__(256) void k_posvec(const float* __restrict__ A0,
    const float* __restrict__ A1, bf16* __restrict__ Pw) {
  __shared__ float a0s[S_], a1s[S_];
  __shared__ float pbuf[2][Q_];
  const int n = blockIdx.x, t = threadIdx.x;
  a0s[t] = A0[(size_t)n * S_ + t];
  a0s[t + 256] = A0[(size_t)n * S_ + t + 256];
  a1s[t] = A1[(size_t)n * S_ + t];
  a1s[t + 256] = A1[(size_t)n * S_ + t + 256];
  float p = (t == 0) ? 1.f : 0.f;
  __syncthreads();
  for (int s8 = 0; s8 < S_; s8 += 8) {
    float emit[8];
#pragma unroll
    for (int jj = 0; jj < 8; ++jj) {
      const int s = s8 + jj;
      pbuf[jj & 1][t] = p;
      __syncthreads();
      float pm1 = pbuf[jj & 1][(t + Q_ - 1) & (Q_ - 1)];
      float a0 = a0s[s], a1 = a1s[s];
      emit[jj] = p * a1;
      p = fmaf(pm1, a1, p * a0);
    }
    bf16x8 v;
#pragma unroll
    for (int jj = 0; jj < 8; ++jj) v[jj] = (bf16)emit[jj];
    *(bf16x8*)(Pw + ((size_t)n * Q_ + t) * S_ + s8) = v;
  }
}

// ---------------- stage 3: queue einsum ----------------
__global__ __launch_bounds__(256) void k_queue(const bf16* __restrict__ Pw,
    const float* __restrict__ mem, bf16* __restrict__ qout) {
  __shared__ bf16 bt[64 * 32];
  const int bid = blockIdx.x;
  const int n = bid >> 5, qt = (bid >> 3) & 3, ct = bid & 7;
  const int q0 = qt * 64, c0 = ct * 64;
  const int t = threadIdx.x, wid = t >> 6, lane = t & 63;
  const int lrow = lane & 15, lkb = lane >> 4;
  f32x4 acc[4] = {};
  const bf16* arow = Pw + ((size_t)n * Q_ + q0 + wid * 16 + lrow) * S_ + lkb * 8;
  const int sl = t >> 3, cb = (t & 7) * 8;
  const float* msrc = mem + ((size_t)sl * N_ + n) * C_ + c0 + cb;
  for (int kb = 0; kb < 16; ++kb) {
    float4 f0 = *(const float4*)(msrc + (size_t)kb * 32 * N_ * C_);
    float4 f1 = *(const float4*)(msrc + (size_t)kb * 32 * N_ * C_ + 4);
    __syncthreads();
    float fv[8] = {f0.x, f0.y, f0.z, f0.w, f1.x, f1.y, f1.z, f1.w};
#pragma unroll
    for (int jw = 0; jw < 8; ++jw) {
      const int row = cb + jw;
      bt[row * 32 + ((((sl >> 3) ^ (row & 3)) << 3) | (sl & 7))] = (bf16)fv[jw];
    }
    __syncthreads();
    bf16x8 a = *(const bf16x8*)(arow + kb * 32);
#pragma unroll
    for (int cs = 0; cs < 4; ++cs) {
      const int row = cs * 16 + lrow;
      bf16x8 b = *(const bf16x8*)(&bt[row * 32 + ((lkb ^ (row & 3)) << 3)]);
      acc[cs] = __builtin_amdgcn_mfma_f32_16x16x32_bf16(a, b, acc[cs], 0, 0, 0);
    }
  }
#pragma unroll
  for (int cs = 0; cs < 4; ++cs) {
#pragma unroll
    for (int r = 0; r < 4; ++r) {
      const int q = q0 + wid * 16 + (lane >> 4) * 4 + r;
      const int c = c0 + cs * 16 + lrow;
      qout[((size_t)q * N_ + n) * C_ + c] = (bf16)acc[cs][r];
    }
  }
}

// ---------------- stage 4: LSTM (persistent, 64 WGs, flag-fused sync) ----------------
// Wave roles: wid<2 -> x-matrix (W_ih), wid>=2 -> h-matrix (W_hh); blk = wid&1 = M-block.
// All cross-WG traffic (H, flags) via sc0/sc1 (LLC, memory-side coherent). No fences.
__global__ __launch_bounds__(256, 1) void k_lstm(
    const bf16* __restrict__ queue, const float* __restrict__ Wih,
    const float* __restrict__ Whh, const float* __restrict__ bih,
    const float* __restrict__ bhh, bf16* __restrict__ H,
    bf16* __restrict__ hs, int* __restrict__ flags) {
  __shared__ float gx[2][32][33];
  __shared__ float gh[2][32][33];
  __shared__ float bias[32];
  const int w = blockIdx.x, t = threadIdx.x;
  const int wid = t >> 6, lane = t & 63;
  const int mat = wid >> 1;   // 0 = x (W_ih), 1 = h (W_hh)
  const int blk = wid & 1;    // rows blk*32 .. +32

  // ---- weight B-fragments -> registers (held across all 256 steps) ----
  const int col = lane & 31;                 // gate col j: gate=j&3, ch=w*8+(j>>2)
  const int kg = (lane >> 5) * 8;
  const int wr = (col & 3) * 512 + w * 8 + (col >> 2);
  const float* Wsrc = (mat ? Whh : Wih) + (size_t)wr * C_ + kg;
  bf16x8 bw[32];
#pragma unroll
  for (int kb = 0; kb < 32; ++kb) {
    float4 wa = *(const float4*)(Wsrc + kb * 16);
    float4 wb = *(const float4*)(Wsrc + kb * 16 + 4);
    bf16x8 v;
    v[0] = (bf16)wa.x; v[1] = (bf16)wa.y; v[2] = (bf16)wa.z; v[3] = (bf16)wa.w;
    v[4] = (bf16)wb.x; v[5] = (bf16)wb.y; v[6] = (bf16)wb.z; v[7] = (bf16)wb.w;
    bw[kb] = v;
  }
  if (t < 32) {
    const int rr = (t & 3) * 512 + w * 8 + (t >> 2);
    bias[t] = bih[rr] + bhh[rr];
  }
  // zero H[0] row n=w (sc1 stores), publish flag=1
  __hip_atomic_store((unsigned*)H + (size_t)w * (C_ / 2) + t, 0u,
                     __ATOMIC_RELAXED, __HIP_MEMORY_SCOPE_AGENT);
  asm volatile("s_waitcnt vmcnt(0)" ::: "memory");
  __syncthreads();
  if (t == 0)
    __hip_atomic_store(flags + w, 1, __ATOMIC_RELAXED, __HIP_MEMORY_SCOPE_AGENT);
  if (wid == 0) {
    while (!__all(__hip_atomic_load(flags + lane, __ATOMIC_RELAXED,
                                    __HIP_MEMORY_SCOPE_AGENT) >= 1)) {}
  }
  __syncthreads();

  float cs0 = 0.f, cs1 = 0.f;
  const int en = t >> 2, ep = t & 3;       // elementwise: n = en, channels w*8+2ep,+1
  const int eb = en >> 5, er = en & 31;
  const int j0 = ep * 8;

  bf16x8 xf[32];  // x A-fragments, prefetched one step ahead
  if (mat == 0) {
    const bf16* xb = queue + ((size_t)0 * N_ + blk * 32 + (lane & 31)) * C_ + kg;
#pragma unroll
    for (int kb = 0; kb < 32; ++kb) xf[kb] = *(const bf16x8*)(xb + kb * 16);
  }

  for (int step = 0; step < Q_; ++step) {
    const int cur = step & 1, nxt = cur ^ 1;
    f32x16 acc[4] = {};
    if (mat == 1) {
      // ---- h-part: sc1 loads straight into A-fragments ----
      const bf16* hb = H + ((size_t)cur * N_ + blk * 32 + (lane & 31)) * C_ + kg;
      bf16x8 hf[32];
#pragma unroll
      for (int kb = 0; kb < 32; ++kb)
        asm volatile("global_load_dwordx4 %0, %1, off offset:%2 sc0 sc1"
                     : "=v"(hf[kb]) : "v"(hb), "i"(kb * 32));
      asm volatile("s_waitcnt vmcnt(0)" ::: "memory");
      __builtin_amdgcn_sched_barrier(0);
#pragma unroll
      for (int kb = 0; kb < 32; ++kb)
        acc[kb & 3] = __builtin_amdgcn_mfma_f32_32x32x16_bf16(hf[kb], bw[kb], acc[kb & 3], 0, 0, 0);
      f32x16 asum = (acc[0] + acc[1]) + (acc[2] + acc[3]);
#pragma unroll
      for (int rg = 0; rg < 16; ++rg) {
        const int rl = (rg & 3) + 8 * (rg >> 2) + 4 * (lane >> 5);
        gh[blk][rl][col] = asum[rg];
      }
    } else {
      // ---- x-part: prefetched fragments ----
#pragma unroll
      for (int kb = 0; kb < 32; ++kb)
        acc[kb & 3] = __builtin_amdgcn_mfma_f32_32x32x16_bf16(xf[kb], bw[kb], acc[kb & 3], 0, 0, 0);
      f32x16 asum = (acc[0] + acc[1]) + (acc[2] + acc[3]);
#pragma unroll
      for (int rg = 0; rg < 16; ++rg) {
        const int rl = (rg & 3) + 8 * (rg >> 2) + 4 * (lane >> 5);
        gx[blk][rl][col] = asum[rg];
      }
      if (step + 1 < Q_) {  // prefetch next step's x (static data, hides L2 latency)
        const bf16* xb = queue + ((size_t)(step + 1) * N_ + blk * 32 + (lane & 31)) * C_ + kg;
#pragma unroll
        for (int kb = 0; kb < 32; ++kb) xf[kb] = *(const bf16x8*)(xb + kb * 16);
      }
    }
    __syncthreads();  // S1: gates ready in LDS

    {  // elementwise: n=en, channels c=w*8+2ep, +1; c-state in registers
      float gi = gx[eb][er][j0 + 0] + gh[eb][er][j0 + 0] + bias[j0 + 0];
      float gf = gx[eb][er][j0 + 1] + gh[eb][er][j0 + 1] + bias[j0 + 1];
      float gg = gx[eb][er][j0 + 2] + gh[eb][er][j0 + 2] + bias[j0 + 2];
      float go = gx[eb][er][j0 + 3] + gh[eb][er][j0 + 3] + bias[j0 + 3];
      cs0 = sigf(gf) * cs0 + sigf(gi) * tanhf_(gg);
      float h0v = sigf(go) * tanhf_(cs0);
      gi = gx[eb][er][j0 + 4] + gh[eb][er][j0 + 4] + bias[j0 + 4];
      gf = gx[eb][er][j0 + 5] + gh[eb][er][j0 + 5] + bias[j0 + 5];
      gg = gx[eb][er][j0 + 6] + gh[eb][er][j0 + 6] + bias[j0 + 6];
      go = gx[eb][er][j0 + 7] + gh[eb][er][j0 + 7] + bias[j0 + 7];
      cs1 = sigf(gf) * cs1 + sigf(gi) * tanhf_(gg);
      float h1v = sigf(go) * tanhf_(cs1);
      unsigned lo = __builtin_bit_cast(unsigned short, (bf16)h0v);
      unsigned hi = __builtin_bit_cast(unsigned short, (bf16)h1v);
      unsigned hp = (hi << 16) | lo;
      const unsigned hoff = ((unsigned)nxt * N_ + en) * (C_ / 2) + w * 4 + ep;
      __hip_atomic_store((unsigned*)H + hoff, hp, __ATOMIC_RELAXED, __HIP_MEMORY_SCOPE_AGENT);
      *((unsigned*)hs + ((size_t)step * N_ + en) * (C_ / 2) + w * 4 + ep) = hp;
    }
    asm volatile("s_waitcnt vmcnt(0)" ::: "memory");  // per-wave drain of H/hs stores
    __syncthreads();  // S2: all waves' h stores at LLC

    if (step < Q_ - 1) {
      if (t == 0)
        __hip_atomic_store(flags + w, step + 2, __ATOMIC_RELAXED, __HIP_MEMORY_SCOPE_AGENT);
      if (wid == 0) {
        while (!__all(__hip_atomic_load(flags + lane, __ATOMIC_RELAXED,
                                        __HIP_MEMORY_SCOPE_AGENT) >= step + 2)) {}
      }
      __syncthreads();  // S3: h for step+1 visible
    }
  }
}

// ---------------- stage 5: LayerNorm + decode ----------------
__global__ __launch_bounds__(256) void k_lndec(const bf16* __restrict__ hs,
    const float* __restrict__ gamma, const float* __restrict__ beta,
    const float* __restrict__ Wdec, const float* __restrict__ bdec,
    float* __restrict__ out) {
  const int wid = threadIdx.x >> 6, lane = threadIdx.x & 63;
  const int row = blockIdx.x * 4 + wid;  // t*64 + n
  const bf16* hrow = hs + (size_t)row * C_ + lane * 8;
  bf16x8 hv = *(const bf16x8*)hrow;
  float h[8];
  float sm = 0.f, sq = 0.f;
#pragma unroll
  for (int j = 0; j < 8; ++j) {
    h[j] = (float)hv[j];
    sm += h[j];
    sq += h[j] * h[j];
  }
#pragma unroll
  for (int m = 32; m >= 1; m >>= 1) {
    sm += __shfl_xor(sm, m);
    sq += __shfl_xor(sq, m);
  }
  const float mu = sm * (1.f / C_);
  const float var = sq * (1.f / C_) - mu * mu;
  const float rs = 1.f / sqrtf(var + 1e-5f);
  float o[V_] = {};
#pragma unroll
  for (int j = 0; j < 8; ++j) {
    const int cj = lane * 8 + j;
    const float nv = (h[j] - mu) * rs * gamma[cj] + beta[cj];
    const float* wr = Wdec + (size_t)cj * V_;
#pragma unroll
    for (int v = 0; v < V_; ++v) o[v] += nv * wr[v];
  }
#pragma unroll
  for (int v = 0; v < V_; ++v) {
#pragma unroll
    for (int m = 32; m >= 1; m >>= 1) o[v] += __shfl_xor(o[v], m);
  }
  if (lane == 0) {
#pragma unroll
    for (int v = 0; v < V_; ++v) out[(size_t)row * V_ + v] = o[v] + bdec[v];
  }
}

extern "C" void kernel_launch(void* const* d_in, const int* in_sizes, int n_in,
                              void* d_out, int out_size, void* d_ws, size_t ws_size,
                              hipStream_t stream) {
  (void)in_sizes; (void)n_in; (void)out_size; (void)ws_size;
  const float* mem  = (const float*)d_in[0];
  const float* Wact = (const float*)d_in[1];
  const float* bact = (const float*)d_in[2];
  const float* Wih  = (const float*)d_in[3];
  const float* Whh  = (const float*)d_in[4];
  const float* bih  = (const float*)d_in[5];
  const float* bhh  = (const float*)d_in[6];
  const float* gam  = (const float*)d_in[7];
  const float* bet  = (const float*)d_in[8];
  const float* Wdec = (const float*)d_in[9];
  const float* bdec = (const float*)d_in[10];
  float* out = (float*)d_out;

  char* ws = (char*)d_ws;
  float* A0 = (float*)(ws + OFF_A0);
  float* A1 = (float*)(ws + OFF_A1);
  bf16* Pw  = (bf16*)(ws + OFF_PW);
  bf16* qu  = (bf16*)(ws + OFF_QU);
  bf16* H   = (bf16*)(ws + OFF_H);
  bf16* hs  = (bf16*)(ws + OFF_HS);
  int* bar  = (int*)(ws + OFF_BAR);

  hipMemsetAsync(bar, 0, 256, stream);
  k_actions<<<(S_ * N_) / 4, 256, 0, stream>>>(mem, Wact, bact, A0, A1);
  k_posvec<<<N_, 256, 0, stream>>>(A0, A1, Pw);
  k_queue<<<N_ * 32, 256, 0, stream>>>(Pw, mem, qu);
  k_lstm<<<NWG_LSTM, 256, 0, stream>>>(qu, Wih, Whh, bih, bhh, H, hs, bar);
  k_lndec<<<(Q_ * N_) / 4, 256, 0, stream>>>(hs, gam, bet, Wdec, bdec, out);
}

// Round 4
// 1675.193 us; speedup vs baseline: 1.9553x; 1.0574x over previous
//
#include <hip/hip_runtime.h>
#include <hip/hip_bf16.h>

typedef __bf16 bf16;
typedef __bf16 bf16x8 __attribute__((ext_vector_type(8)));
typedef float f32x4 __attribute__((ext_vector_type(4)));
typedef float f32x16 __attribute__((ext_vector_type(16)));

#define S_ 512
#define N_ 64
#define C_ 512
#define V_ 10
#define Q_ 256

// ---- workspace layout (bytes) ----
#define OFF_A0   ((size_t)0)
#define OFF_A1   (OFF_A0 + (size_t)S_ * N_ * 4)
#define OFF_PW   (OFF_A1 + (size_t)S_ * N_ * 4)            // bf16 [N][Q][S]
#define OFF_QU   (OFF_PW + (size_t)N_ * Q_ * S_ * 2)       // bf16 [Q][N][C]
#define OFF_H    (OFF_QU + (size_t)Q_ * N_ * C_ * 2)       // bf16 [2][N][C]
#define OFF_HS   (OFF_H + (size_t)2 * N_ * C_ * 2)         // bf16 [Q][N][C]
#define OFF_BAR  (OFF_HS + (size_t)Q_ * N_ * C_ * 2)       // ctrl: done + flags

__device__ __forceinline__ float sigf(float x) { return 1.f / (1.f + __expf(-x)); }
__device__ __forceinline__ float tanhf_(float x) { return 1.f - 2.f / (__expf(2.f * x) + 1.f); }

// ---------------- stage 1: action softmax ----------------
__global__ __launch_bounds__(256) void k_actions(const float* __restrict__ mem,
    const float* __restrict__ Wact, const float* __restrict__ bact,
    float* __restrict__ A0, float* __restrict__ A1) {
  const int wid = threadIdx.x >> 6, lane = threadIdx.x & 63;
  const int row = blockIdx.x * 4 + wid;          // row = s*64 + n
  const int s = row >> 6, n = row & 63;
  const float* mrow = mem + (size_t)row * C_ + lane * 8;
  const float* wrow = Wact + (size_t)lane * 16;
  float4 m0 = *(const float4*)(mrow);
  float4 m1 = *(const float4*)(mrow + 4);
  float d0 = 0.f, d1 = 0.f;
  float mv[8] = {m0.x, m0.y, m0.z, m0.w, m1.x, m1.y, m1.z, m1.w};
#pragma unroll
  for (int j = 0; j < 8; ++j) {
    d0 += mv[j] * wrow[j * 2 + 0];
    d1 += mv[j] * wrow[j * 2 + 1];
  }
#pragma unroll
  for (int m = 32; m >= 1; m >>= 1) {
    d0 += __shfl_xor(d0, m);
    d1 += __shfl_xor(d1, m);
  }
  if (lane == 0) {
    float l0 = d0 + bact[0], l1 = d1 + bact[1];
    float mx = fmaxf(l0, l1);
    float e0 = __expf(l0 - mx), e1 = __expf(l1 - mx);
    float inv = 1.f / (e0 + e1);
    A0[(size_t)n * S_ + s] = e0 * inv;
    A1[(size_t)n * S_ + s] = e1 * inv;
  }
}

// ---------------- stage 2: posvec scan ----------------
__global__ __launch_bounds__(256) void k_posvec(const float* __restrict__ A0,
    const float* __restrict__ A1, bf16* __restrict__ Pw) {
  __shared__ float a0s[S_], a1s[S_];
  __shared__ float pbuf[2][Q_];
  const int n = blockIdx.x, t = threadIdx.x;
  a0s[t] = A0[(size_t)n * S_ + t];
  a0s[t + 256] = A0[(size_t)n * S_ + t + 256];
  a1s[t] = A1[(size_t)n * S_ + t];
  a1s[t + 256] = A1[(size_t)n * S_ + t + 256];
  float p = (t == 0) ? 1.f : 0.f;
  __syncthreads();
  for (int s8 = 0; s8 < S_; s8 += 8) {
    float emit[8];
#pragma unroll
    for (int jj = 0; jj < 8; ++jj) {
      const int s = s8 + jj;
      pbuf[jj & 1][t] = p;
      __syncthreads();
      float pm1 = pbuf[jj & 1][(t + Q_ - 1) & (Q_ - 1)];
      float a0 = a0s[s], a1 = a1s[s];
      emit[jj] = p * a1;
      p = fmaf(pm1, a1, p * a0);
    }
    bf16x8 v;
#pragma unroll
    for (int jj = 0; jj < 8; ++jj) v[jj] = (bf16)emit[jj];
    *(bf16x8*)(Pw + ((size_t)n * Q_ + t) * S_ + s8) = v;
  }
}

// ---------------- stage 3: queue einsum ----------------
__global__ __launch_bounds__(256) void k_queue(const bf16* __restrict__ Pw,
    const float* __restrict__ mem, bf16* __restrict__ qout) {
  __shared__ bf16 bt[64 * 32];
  const int bid = blockIdx.x;
  const int n = bid >> 5, qt = (bid >> 3) & 3, ct = bid & 7;
  const int q0 = qt * 64, c0 = ct * 64;
  const int t = threadIdx.x, wid = t >> 6, lane = t & 63;
  const int lrow = lane & 15, lkb = lane >> 4;
  f32x4 acc[4] = {};
  const bf16* arow = Pw + ((size_t)n * Q_ + q0 + wid * 16 + lrow) * S_ + lkb * 8;
  const int sl = t >> 3, cb = (t & 7) * 8;
  const float* msrc = mem + ((size_t)sl * N_ + n) * C_ + c0 + cb;
  for (int kb = 0; kb < 16; ++kb) {
    float4 f0 = *(const float4*)(msrc + (size_t)kb * 32 * N_ * C_);
    float4 f1 = *(const float4*)(msrc + (size_t)kb * 32 * N_ * C_ + 4);
    __syncthreads();
    float fv[8] = {f0.x, f0.y, f0.z, f0.w, f1.x, f1.y, f1.z, f1.w};
#pragma unroll
    for (int jw = 0; jw < 8; ++jw) {
      const int row = cb + jw;
      bt[row * 32 + ((((sl >> 3) ^ (row & 3)) << 3) | (sl & 7))] = (bf16)fv[jw];
    }
    __syncthreads();
    bf16x8 a = *(const bf16x8*)(arow + kb * 32);
#pragma unroll
    for (int cs = 0; cs < 4; ++cs) {
      const int row = cs * 16 + lrow;
      bf16x8 b = *(const bf16x8*)(&bt[row * 32 + ((lkb ^ (row & 3)) << 3)]);
      acc[cs] = __builtin_amdgcn_mfma_f32_16x16x32_bf16(a, b, acc[cs], 0, 0, 0);
    }
  }
#pragma unroll
  for (int cs = 0; cs < 4; ++cs) {
#pragma unroll
    for (int r = 0; r < 4; ++r) {
      const int q = q0 + wid * 16 + (lane >> 4) * 4 + r;
      const int c = c0 + cs * 16 + lrow;
      qout[((size_t)q * N_ + n) * C_ + c] = (bf16)acc[cs][r];
    }
  }
}

// ---------------- stage 4: LSTM (64 workers + 192 heater WGs) ----------------
// Workers (bid<64): round-2 LLC flag protocol, tightened:
//  - x-waves (wid 0,1) never poll; gated via S1/S2.
//  - per-WG flag published via LDS wave-counter right after each wave's own
//    vmcnt drain (no syncthreads on the flag path).
//  - drain excludes hs store (vmcnt(1): H store is older, acked first - m135).
//  - h-load -> MFMA overlap via counted vmcnt chunks.
// Heaters (bid>=64): register FMA spin to hold clocks up; poll done flag.
__global__ __launch_bounds__(256, 1) void k_lstm(
    const bf16* __restrict__ queue, const float* __restrict__ Wih,
    const float* __restrict__ Whh, const float* __restrict__ bih,
    const float* __restrict__ bhh, bf16* __restrict__ H,
    bf16* __restrict__ hs, int* __restrict__ ctrl) {
  const int bid = blockIdx.x, t = threadIdx.x;

  if (bid >= 64) {  // ---------- heater ----------
    float x0 = 1.f + t, x1 = 2.f + t, x2 = 3.f + t, x3 = 4.f + t;
    for (int outer = 0; outer < 10000; ++outer) {
      int d;
      asm volatile("global_load_dword %0, %1, off sc0 sc1" : "=v"(d) : "v"(ctrl));
#pragma unroll
      for (int i = 0; i < 500; ++i) {
        x0 = fmaf(x0, 0.9999999f, 1e-7f);
        x1 = fmaf(x1, 0.9999998f, 2e-7f);
        x2 = fmaf(x2, 1.0000001f, 3e-7f);
        x3 = fmaf(x3, 1.0000002f, 4e-7f);
      }
      asm volatile("s_waitcnt vmcnt(0)" ::: "memory");
      if (d) break;
    }
    asm volatile("" :: "v"(x0), "v"(x1), "v"(x2), "v"(x3));
    return;
  }

  // ---------- worker ----------
  __shared__ float gx[2][2][32][33];  // [step parity][Mblk][row][col]
  __shared__ float gh[2][32][33];     // [Mblk][row][col]
  __shared__ float bias[32];
  __shared__ int ldsCnt[Q_];
  __shared__ int ldsCnt0;
  int* flags = ctrl + 64;
  const int w = bid;
  const int wid = t >> 6, lane = t & 63;
  const int mat = wid >> 1;   // 0 = x (W_ih), 1 = h (W_hh)
  const int blk = wid & 1;    // n-rows blk*32 .. +32

  // weight B-fragments -> registers (held across all steps)
  const int col = lane & 31;                 // gate col j: gate=j&3, ch=w*8+(j>>2)
  const int kg = (lane >> 5) * 8;
  const int wr = (col & 3) * 512 + w * 8 + (col >> 2);
  const float* Wsrc = (mat ? Whh : Wih) + (size_t)wr * C_ + kg;
  bf16x8 bw[32];
#pragma unroll
  for (int kb = 0; kb < 32; ++kb) {
    float4 wa = *(const float4*)(Wsrc + kb * 16);
    float4 wb = *(const float4*)(Wsrc + kb * 16 + 4);
    bf16x8 v;
    v[0] = (bf16)wa.x; v[1] = (bf16)wa.y; v[2] = (bf16)wa.z; v[3] = (bf16)wa.w;
    v[4] = (bf16)wb.x; v[5] = (bf16)wb.y; v[6] = (bf16)wb.z; v[7] = (bf16)wb.w;
    bw[kb] = v;
  }
  if (t < 32) {
    const int rr = (t & 3) * 512 + w * 8 + (t >> 2);
    bias[t] = bih[rr] + bhh[rr];
  }
  ldsCnt[t] = 0;
  if (t == 0) ldsCnt0 = 0;
  __syncthreads();

  // zero this WG's H[0] slice (ch w*8..w*8+8 for all n), then publish flag=1
  const int en = t >> 2, ep = t & 3;         // elementwise item: n=en, ch pair 2ep
  {
    unsigned* Hp = (unsigned*)H + ((size_t)0 * N_ + en) * (C_ / 2) + w * 4 + ep;
    unsigned z = 0;
    asm volatile("global_store_dword %0, %1, off sc0 sc1" :: "v"(Hp), "v"(z) : "memory");
    asm volatile("s_waitcnt vmcnt(0)" ::: "memory");
    if (lane == 0) {
      if (atomicAdd(&ldsCnt0, 1) == 3) {
        int one = 1;
        int* fp = flags + w;
        asm volatile("global_store_dword %0, %1, off sc0 sc1" :: "v"(fp), "v"(one) : "memory");
      }
    }
  }

  float cs0 = 0.f, cs1 = 0.f;
  const int eb = en >> 5, er = en & 31, j0 = ep * 8;

  bf16x8 xf[32];  // x A-fragments (holds x(step+1) at loop top)
  if (mat == 0) {
    const bf16* xb = queue + ((size_t)0 * N_ + blk * 32 + (lane & 31)) * C_ + kg;
#pragma unroll
    for (int kb = 0; kb < 32; ++kb) xf[kb] = *(const bf16x8*)(xb + kb * 16);
    {  // gx for step 0
      f32x16 acc[4] = {};
#pragma unroll
      for (int kb = 0; kb < 32; ++kb)
        acc[kb & 3] = __builtin_amdgcn_mfma_f32_32x32x16_bf16(xf[kb], bw[kb], acc[kb & 3], 0, 0, 0);
      f32x16 asum = (acc[0] + acc[1]) + (acc[2] + acc[3]);
#pragma unroll
      for (int rg = 0; rg < 16; ++rg) {
        const int rl = (rg & 3) + 8 * (rg >> 2) + 4 * (lane >> 5);
        gx[0][blk][rl][col] = asum[rg];
      }
    }
    const bf16* xb1 = queue + ((size_t)1 * N_ + blk * 32 + (lane & 31)) * C_ + kg;
#pragma unroll
    for (int kb = 0; kb < 32; ++kb) xf[kb] = *(const bf16x8*)(xb1 + kb * 16);
  }

  for (int step = 0; step < Q_; ++step) {
    const int p = step & 1;
    const int cur = p, nxt = p ^ 1;
    if (mat == 1) {
      // ---- poll global flags (h-waves only) ----
      {
        int v;
        int* fa = flags + lane;
        do {
          asm volatile("global_load_dword %0, %1, off sc0 sc1" : "=v"(v) : "v"(fa));
          asm volatile("s_waitcnt vmcnt(0)" ::: "memory");
        } while (!__all(v >= step + 1));
      }
      __builtin_amdgcn_sched_barrier(0);
      // ---- h-load (LLC) with chunked MFMA overlap ----
      const bf16* hb = H + ((size_t)cur * N_ + blk * 32 + (lane & 31)) * C_ + kg;
      bf16x8 hf[32];
#pragma unroll
      for (int kb = 0; kb < 32; ++kb)
        asm volatile("global_load_dwordx4 %0, %1, off offset:%2 sc0 sc1"
                     : "=v"(hf[kb]) : "v"(hb), "i"(kb * 32));
      f32x16 acc[4] = {};
      asm volatile("s_waitcnt vmcnt(24)" ::: "memory");
      __builtin_amdgcn_sched_barrier(0);
#pragma unroll
      for (int kb = 0; kb < 8; ++kb)
        acc[kb & 3] = __builtin_amdgcn_mfma_f32_32x32x16_bf16(hf[kb], bw[kb], acc[kb & 3], 0, 0, 0);
      asm volatile("s_waitcnt vmcnt(16)" ::: "memory");
      __builtin_amdgcn_sched_barrier(0);
#pragma unroll
      for (int kb = 8; kb < 16; ++kb)
        acc[kb & 3] = __builtin_amdgcn_mfma_f32_32x32x16_bf16(hf[kb], bw[kb], acc[kb & 3], 0, 0, 0);
      asm volatile("s_waitcnt vmcnt(8)" ::: "memory");
      __builtin_amdgcn_sched_barrier(0);
#pragma unroll
      for (int kb = 16; kb < 24; ++kb)
        acc[kb & 3] = __builtin_amdgcn_mfma_f32_32x32x16_bf16(hf[kb], bw[kb], acc[kb & 3], 0, 0, 0);
      asm volatile("s_waitcnt vmcnt(0)" ::: "memory");
      __builtin_amdgcn_sched_barrier(0);
#pragma unroll
      for (int kb = 24; kb < 32; ++kb)
        acc[kb & 3] = __builtin_amdgcn_mfma_f32_32x32x16_bf16(hf[kb], bw[kb], acc[kb & 3], 0, 0, 0);
      f32x16 asum = (acc[0] + acc[1]) + (acc[2] + acc[3]);
#pragma unroll
      for (int rg = 0; rg < 16; ++rg) {
        const int rl = (rg & 3) + 8 * (rg >> 2) + 4 * (lane >> 5);
        gh[blk][rl][col] = asum[rg];
      }
    } else if (step + 1 < Q_) {
      // ---- x-waves: gates for step+1 from prefetched xf ----
      f32x16 acc[4] = {};
#pragma unroll
      for (int kb = 0; kb < 32; ++kb)
        acc[kb & 3] = __builtin_amdgcn_mfma_f32_32x32x16_bf16(xf[kb], bw[kb], acc[kb & 3], 0, 0, 0);
      f32x16 asum = (acc[0] + acc[1]) + (acc[2] + acc[3]);
#pragma unroll
      for (int rg = 0; rg < 16; ++rg) {
        const int rl = (rg & 3) + 8 * (rg >> 2) + 4 * (lane >> 5);
        gx[p ^ 1][blk][rl][col] = asum[rg];
      }
    }
    __syncthreads();  // S1: gh + gx[p] ready

    {  // elementwise: n=en, channels w*8+2ep, +1; c-state in registers
      float g0 = gx[p][eb][er][j0 + 0] + gh[eb][er][j0 + 0] + bias[j0 + 0];
      float g1 = gx[p][eb][er][j0 + 1] + gh[eb][er][j0 + 1] + bias[j0 + 1];
      float g2 = gx[p][eb][er][j0 + 2] + gh[eb][er][j0 + 2] + bias[j0 + 2];
      float g3 = gx[p][eb][er][j0 + 3] + gh[eb][er][j0 + 3] + bias[j0 + 3];
      cs0 = sigf(g1) * cs0 + sigf(g0) * tanhf_(g2);
      float h0v = sigf(g3) * tanhf_(cs0);
      float g4 = gx[p][eb][er][j0 + 4] + gh[eb][er][j0 + 4] + bias[j0 + 4];
      float g5 = gx[p][eb][er][j0 + 5] + gh[eb][er][j0 + 5] + bias[j0 + 5];
      float g6 = gx[p][eb][er][j0 + 6] + gh[eb][er][j0 + 6] + bias[j0 + 6];
      float g7 = gx[p][eb][er][j0 + 7] + gh[eb][er][j0 + 7] + bias[j0 + 7];
      cs1 = sigf(g5) * cs1 + sigf(g4) * tanhf_(g6);
      float h1v = sigf(g7) * tanhf_(cs1);
      unsigned lo = __builtin_bit_cast(unsigned short, (bf16)h0v);
      unsigned hi = __builtin_bit_cast(unsigned short, (bf16)h1v);
      unsigned hp = (hi << 16) | lo;
      unsigned* Hp = (unsigned*)H + ((size_t)nxt * N_ + en) * (C_ / 2) + w * 4 + ep;
      asm volatile("global_store_dword %0, %1, off sc0 sc1" :: "v"(Hp), "v"(hp) : "memory");
      *((unsigned*)hs + ((size_t)step * N_ + en) * (C_ / 2) + w * 4 + ep) = hp;
    }
    asm volatile("s_waitcnt vmcnt(1)" ::: "memory");  // H acked; hs may linger
    if (step + 1 < Q_) {
      if (lane == 0) {
        if (atomicAdd(&ldsCnt[step], 1) == 3) {  // last wave of this WG
          int fv = step + 2;
          int* fp = flags + w;
          asm volatile("global_store_dword %0, %1, off sc0 sc1" :: "v"(fp), "v"(fv) : "memory");
        }
      }
      if (mat == 0 && step + 2 < Q_) {  // prefetch x(step+2)
        const bf16* xb = queue + ((size_t)(step + 2) * N_ + blk * 32 + (lane & 31)) * C_ + kg;
#pragma unroll
        for (int kb = 0; kb < 32; ++kb) xf[kb] = *(const bf16x8*)(xb + kb * 16);
      }
    }
    __syncthreads();  // S2: fences gx[p^1] overwrite vs this step's reads
  }

  if (t == 0 && bid == 0) {  // release heaters
    int one = 1;
    asm volatile("global_store_dword %0, %1, off sc0 sc1" :: "v"(ctrl), "v"(one) : "memory");
  }
}

// ---------------- stage 5: LayerNorm + decode ----------------
__global__ __launch_bounds__(256) void k_lndec(const bf16* __restrict__ hs,
    const float* __restrict__ gamma, const float* __restrict__ beta,
    const float* __restrict__ Wdec, const float* __restrict__ bdec,
    float* __restrict__ out) {
  const int wid = threadIdx.x >> 6, lane = threadIdx.x & 63;
  const int row = blockIdx.x * 4 + wid;  // t*64 + n
  const bf16* hrow = hs + (size_t)row * C_ + lane * 8;
  bf16x8 hv = *(const bf16x8*)hrow;
  float h[8];
  float sm = 0.f, sq = 0.f;
#pragma unroll
  for (int j = 0; j < 8; ++j) {
    h[j] = (float)hv[j];
    sm += h[j];
    sq += h[j] * h[j];
  }
#pragma unroll
  for (int m = 32; m >= 1; m >>= 1) {
    sm += __shfl_xor(sm, m);
    sq += __shfl_xor(sq, m);
  }
  const float mu = sm * (1.f / C_);
  const float var = sq * (1.f / C_) - mu * mu;
  const float rs = 1.f / sqrtf(var + 1e-5f);
  float o[V_] = {};
#pragma unroll
  for (int j = 0; j < 8; ++j) {
    const int cj = lane * 8 + j;
    const float nv = (h[j] - mu) * rs * gamma[cj] + beta[cj];
    const float* wr = Wdec + (size_t)cj * V_;
#pragma unroll
    for (int v = 0; v < V_; ++v) o[v] += nv * wr[v];
  }
#pragma unroll
  for (int v = 0; v < V_; ++v) {
#pragma unroll
    for (int m = 32; m >= 1; m >>= 1) o[v] += __shfl_xor(o[v], m);
  }
  if (lane == 0) {
#pragma unroll
    for (int v = 0; v < V_; ++v) out[(size_t)row * V_ + v] = o[v] + bdec[v];
  }
}

extern "C" void kernel_launch(void* const* d_in, const int* in_sizes, int n_in,
                              void* d_out, int out_size, void* d_ws, size_t ws_size,
                              hipStream_t stream) {
  (void)in_sizes; (void)n_in; (void)out_size; (void)ws_size;
  const float* mem  = (const float*)d_in[0];
  const float* Wact = (const float*)d_in[1];
  const float* bact = (const float*)d_in[2];
  const float* Wih  = (const float*)d_in[3];
  const float* Whh  = (const float*)d_in[4];
  const float* bih  = (const float*)d_in[5];
  const float* bhh  = (const float*)d_in[6];
  const float* gam  = (const float*)d_in[7];
  const float* bet  = (const float*)d_in[8];
  const float* Wdec = (const float*)d_in[9];
  const float* bdec = (const float*)d_in[10];
  float* out = (float*)d_out;

  char* ws = (char*)d_ws;
  float* A0 = (float*)(ws + OFF_A0);
  float* A1 = (float*)(ws + OFF_A1);
  bf16* Pw  = (bf16*)(ws + OFF_PW);
  bf16* qu  = (bf16*)(ws + OFF_QU);
  bf16* H   = (bf16*)(ws + OFF_H);
  bf16* hs  = (bf16*)(ws + OFF_HS);
  int* ctrl = (int*)(ws + OFF_BAR);

  hipMemsetAsync(ctrl, 0, 4096, stream);
  k_actions<<<(S_ * N_) / 4, 256, 0, stream>>>(mem, Wact, bact, A0, A1);
  k_posvec<<<N_, 256, 0, stream>>>(A0, A1, Pw);
  k_queue<<<N_ * 32, 256, 0, stream>>>(Pw, mem, qu);
  k_lstm<<<256, 256, 0, stream>>>(qu, Wih, Whh, bih, bhh, H, hs, ctrl);
  k_lndec<<<(Q_ * N_) / 4, 256, 0, stream>>>(hs, gam, bet, Wdec, bdec, out);
}